// Round 11
// baseline (228.535 us; speedup 1.0000x reference)
//
#include <hip/hip_runtime.h>
#include <hip/hip_bf16.h>

// Typed-relation MHA, MI355X.  B=2 L=2048 HID=512 NH=8 DH=64 T=3.
// Pipeline: prep -> QKV gemm (writes V^T) -> qt gemm -> flash attn -> out gemm.
// R3/R9: VGPR caps too tight -> spill (WRITE_SIZE balloons). R6: TLP not the fix.
// R10: block-shared LDS-staged K/V -> flash 167->74.6us (theory confirmed).
// R11: flash + setprio around MFMA (T5; stage/compute role split now exists);
//      qkv_gemm -> 128x128 tile (2x MFMA per load window, half the blocks).

typedef __attribute__((ext_vector_type(4))) float f32x4;
typedef __attribute__((ext_vector_type(8))) short bf16x8;
typedef __attribute__((ext_vector_type(4))) unsigned short u16x4;
typedef __attribute__((ext_vector_type(2))) unsigned int u32x2;

static __device__ __forceinline__ unsigned short f2bf(float x) {
  __hip_bfloat16 h = __float2bfloat16(x);
  return *reinterpret_cast<unsigned short*>(&h);
}
static __device__ __forceinline__ unsigned int pk2(float lo, float hi) {
  return (unsigned int)f2bf(lo) | ((unsigned int)f2bf(hi) << 16);
}
static __device__ __forceinline__ bf16x8 ld8(const unsigned short* p) {
  return *reinterpret_cast<const bf16x8*>(p);
}
// async global->LDS, 16B/lane; HW writes lds_base + lane*16 (base must be wave-uniform)
static __device__ __forceinline__ void gload16(const unsigned short* g, unsigned short* l) {
  __builtin_amdgcn_global_load_lds((const __attribute__((address_space(1))) void*)g,
                                   (__attribute__((address_space(3))) void*)l, 16, 0, 0);
}
// swizzled LDS tile read: tile rows are 128B; byte ^= (row&7)<<4 (G4 recipe)
static __device__ __forceinline__ bf16x8 lds_swz(const char* base, int row, int colbyte) {
  return *reinterpret_cast<const bf16x8*>(base + row * 128 + (colbyte ^ ((row & 7) << 4)));
}

// ---------------- P0: prep = W transposes + query cast + typed_ids pack ----------------
__global__ __launch_bounds__(256) void prep(
    const float* __restrict__ query, const int* __restrict__ tids,
    const float* __restrict__ Wq, const float* __restrict__ Wk,
    const float* __restrict__ Wv, const float* __restrict__ Wo,
    const float* __restrict__ tw,
    unsigned short* __restrict__ q_bf,
    unsigned short* __restrict__ WT_bf,     // [3][512 n][512 k]
    unsigned short* __restrict__ WoT_bf,    // [512 n][512 k]
    unsigned short* __restrict__ twT_bf,    // [3][8][64 e][64 d]
    unsigned char* __restrict__ tids2) {    // [B,L,L/4]
  const int bid = blockIdx.x;
  const int t = threadIdx.x;
  if (bid < 280) {
    __shared__ float tile[64][65];
    const float* src; unsigned short* dst; int lds_, ldd_;
    if (bid < 256) {
      const int m = bid >> 6, tl = bid & 63;
      const int k0 = (tl >> 3) * 64, n0 = (tl & 7) * 64;
      const float* W = (m == 0) ? Wq : (m == 1) ? Wk : (m == 2) ? Wv : Wo;
      src = W + k0 * 512 + n0;
      dst = ((m < 3) ? WT_bf + m * 512 * 512 : WoT_bf) + n0 * 512 + k0;
      lds_ = 512; ldd_ = 512;
    } else {
      const int idx = bid - 256;  // t*8+h, 0..23
      src = tw + idx * 4096; dst = twT_bf + idx * 4096;
      lds_ = 64; ldd_ = 64;
    }
#pragma unroll
    for (int p = 0; p < 4; p++) {
      const int i4 = t + p * 256;
      const int row = i4 >> 4, c4 = (i4 & 15) * 4;
      const f32x4 v = *reinterpret_cast<const f32x4*>(src + row * lds_ + c4);
#pragma unroll
      for (int j = 0; j < 4; j++) tile[row][c4 + j] = v[j];
    }
    __syncthreads();
#pragma unroll
    for (int p = 0; p < 2; p++) {
      const int i8 = t + p * 256;
      const int n = i8 >> 3, k8 = (i8 & 7) * 8;
      bf16x8 o;
#pragma unroll
      for (int j = 0; j < 8; j++) o[j] = (short)f2bf(tile[k8 + j][n]);
      *reinterpret_cast<bf16x8*>(dst + n * ldd_ + k8) = o;
    }
    return;
  }
  const int nconv = (gridDim.x - 280) * 256;
  const int tid = (bid - 280) * 256 + t;
  for (int i = tid; i < 4096 * 512 / 4; i += nconv) {
    const f32x4 v = *reinterpret_cast<const f32x4*>(query + (size_t)i * 4);
    u16x4 o;
#pragma unroll
    for (int j = 0; j < 4; j++) o[j] = f2bf(v[j]);
    *reinterpret_cast<u16x4*>(q_bf + (size_t)i * 4) = o;
  }
  for (int i = tid; i < 2 * 2048 * 512 / 4; i += nconv) {
    uchar4 o;
#pragma unroll
    for (int j = 0; j < 4; j++) {
      const int4 v = *reinterpret_cast<const int4*>(tids + (size_t)(i * 4 + j) * 4);
      ((unsigned char*)&o)[j] =
          (unsigned char)((v.x & 3) | ((v.y & 3) << 2) | ((v.z & 3) << 4) | ((v.w & 3) << 6));
    }
    *reinterpret_cast<uchar4*>(tids2 + (size_t)i * 4) = o;
  }
}

// ---------------- P1: fused QKV GEMM, 128x128 tile (R11) ----------------
// grid (32, 12): by>>2 = mat (q/k/v), (by&3)*128 = col-base within mat.
// 4 waves (2x2), per-wave 64x64 = mf4 x nf4 frags, BK=32.
__global__ __launch_bounds__(256, 4) void qkv_gemm(
    const unsigned short* __restrict__ Abf,  // query_bf [4096][512]
    const unsigned short* __restrict__ WT,   // [3][512 n][512 k]
    const float* __restrict__ bq, const float* __restrict__ bk, const float* __restrict__ bv,
    unsigned short* __restrict__ qh, unsigned short* __restrict__ kh,  // [B,H,L,DH]
    unsigned short* __restrict__ vhT) {      // [B,H,DH,L]
  const int m0 = blockIdx.x * 128;
  const int mat = blockIdx.y >> 2;
  const int ncb = (blockIdx.y & 3) * 128;    // col base within mat, 0..384
  const int wave = threadIdx.x >> 6, lane = threadIdx.x & 63;
  const int mw = wave >> 1, nw = wave & 1;
  const int lhi = lane >> 4, llo = lane & 15;
  const unsigned short* WTm = WT + mat * (512 * 512);
  f32x4 acc[4][4];
#pragma unroll
  for (int i = 0; i < 4; i++)
#pragma unroll
    for (int j = 0; j < 4; j++) acc[i][j] = (f32x4){0.f, 0.f, 0.f, 0.f};
  const int arow = m0 + mw * 64 + llo;
  const int brow = ncb + nw * 64 + llo;
  for (int k0 = 0; k0 < 512; k0 += 32) {
    const int kk = k0 + lhi * 8;
    bf16x8 a[4], b[4];
#pragma unroll
    for (int mf = 0; mf < 4; mf++) a[mf] = ld8(Abf + (arow + 16 * mf) * 512 + kk);
#pragma unroll
    for (int nf = 0; nf < 4; nf++) b[nf] = ld8(WTm + (brow + 16 * nf) * 512 + kk);
#pragma unroll
    for (int mf = 0; mf < 4; mf++)
#pragma unroll
      for (int nf = 0; nf < 4; nf++)
        acc[mf][nf] = __builtin_amdgcn_mfma_f32_16x16x32_bf16(a[mf], b[nf], acc[mf][nf], 0, 0, 0);
  }
  const int bb = m0 >> 11, lbase = (m0 & 2047) + mw * 64;
  if (mat == 2) {
    unsigned short* vt0 = vhT + (size_t)(bb * 8) * 64 * 2048;
#pragma unroll
    for (int mf = 0; mf < 4; mf++) {
#pragma unroll
      for (int nf = 0; nf < 4; nf++) {
        const int col = ncb + nw * 64 + 16 * nf + llo;  // 0..511
        const int h = col >> 6, d = col & 63;
        const float bv_ = bv[col];
        const int l0 = lbase + 16 * mf + lhi * 4;
        u32x2 pk;
        pk[0] = pk2(acc[mf][nf][0] + bv_, acc[mf][nf][1] + bv_);
        pk[1] = pk2(acc[mf][nf][2] + bv_, acc[mf][nf][3] + bv_);
        *reinterpret_cast<u32x2*>(vt0 + ((size_t)h * 64 + d) * 2048 + l0) = pk;
      }
    }
    return;
  }
  const float* bias = (mat == 0) ? bq : bk;
  unsigned short* dst = (mat == 0) ? qh : kh;
  const float scale = (mat == 0) ? 0.125f : 1.0f;
#pragma unroll
  for (int mf = 0; mf < 4; mf++) {
#pragma unroll
    for (int nf = 0; nf < 4; nf++) {
      const int col = ncb + nw * 64 + 16 * nf + llo;
      const int h = col >> 6, d = col & 63;
      const float bv_ = bias[col];
#pragma unroll
      for (int r = 0; r < 4; r++) {
        const int l = lbase + 16 * mf + lhi * 4 + r;
        const float val = (acc[mf][nf][r] + bv_) * scale;
        dst[(((size_t)(bb * 8 + h) * 2048) + l) * 64 + d] = f2bf(val);
      }
    }
  }
}

// ---------------- P3: qt = qh @ W_t -> [B,H,T,L,D] ----------------
__global__ __launch_bounds__(256) void qt_gemm(const unsigned short* __restrict__ qh,
                                               const unsigned short* __restrict__ twT,
                                               unsigned short* __restrict__ qt) {
  const int l0 = blockIdx.x * 128;
  const int bh = blockIdx.y;
  const int t = blockIdx.z;
  const int h = bh & 7;
  const int wave = threadIdx.x >> 6, lane = threadIdx.x & 63;
  const int lhi = lane >> 4, llo = lane & 15;
  const unsigned short* A = qh + bh * 2048 * 64;
  const unsigned short* Bt = twT + (t * 8 + h) * 64 * 64;
  const int r0 = l0 + wave * 32;
  f32x4 acc[2][4];
#pragma unroll
  for (int i = 0; i < 2; i++)
#pragma unroll
    for (int j = 0; j < 4; j++) acc[i][j] = (f32x4){0.f, 0.f, 0.f, 0.f};
  bf16x8 a[2][2], b[4][2];
#pragma unroll
  for (int mf = 0; mf < 2; mf++)
#pragma unroll
    for (int kk = 0; kk < 2; kk++)
      a[mf][kk] = ld8(A + (r0 + 16 * mf + llo) * 64 + kk * 32 + lhi * 8);
#pragma unroll
  for (int nf = 0; nf < 4; nf++)
#pragma unroll
    for (int kk = 0; kk < 2; kk++)
      b[nf][kk] = ld8(Bt + (16 * nf + llo) * 64 + kk * 32 + lhi * 8);
#pragma unroll
  for (int mf = 0; mf < 2; mf++)
#pragma unroll
    for (int nf = 0; nf < 4; nf++)
#pragma unroll
      for (int kk = 0; kk < 2; kk++)
        acc[mf][nf] = __builtin_amdgcn_mfma_f32_16x16x32_bf16(a[mf][kk], b[nf][kk], acc[mf][nf], 0, 0, 0);
  unsigned short* dst = qt + (bh * 3 + t) * 2048 * 64;
#pragma unroll
  for (int mf = 0; mf < 2; mf++)
#pragma unroll
    for (int nf = 0; nf < 4; nf++)
#pragma unroll
      for (int r = 0; r < 4; r++)
        dst[(r0 + 16 * mf + lhi * 4 + r) * 64 + 16 * nf + llo] = f2bf(acc[mf][nf][r]);
}

// ---------------- P4: flash attention, block-shared LDS-staged K/V + setprio ----------------
// grid 512: bh = bid&15, qtile = bid>>4. Block 512 thr = 8 waves:
// qs = w>>1 (4 q-subtiles x 16 rows), s = w&1 (k-phase half of each staged tile).
__global__ __launch_bounds__(512, 4) void flash_attn(
    const unsigned short* __restrict__ qt,    // [B,H,3,L,D] (scaled)
    const unsigned short* __restrict__ kh,    // [B,H,L,D]
    const unsigned short* __restrict__ vhT,   // [B,H,D,L]
    const unsigned char* __restrict__ tids2,  // [B,L,L/4] 2-bit codes
    const float* __restrict__ bias,           // [B,L]
    unsigned short* __restrict__ xout) {      // [B,H,L,D]
  __shared__ char smem[43008];  // dbuf 2x16KB (K 8KB + V 8KB each) + pbuf 8x1280B
  const int bh = blockIdx.x & 15;
  const int qtile = blockIdx.x >> 4;
  const int b = bh >> 3;
  const int w = threadIdx.x >> 6;
  const int qs = w >> 1, s = w & 1;
  const int lane = threadIdx.x & 63;
  const int lhi = lane >> 4, llo = lane & 15;
  const int q0g = qtile * 64 + qs * 16;
  const unsigned short* khb = kh + (size_t)bh * 2048 * 64;
  const unsigned short* vtb = vhT + (size_t)bh * 64 * 2048;
  const unsigned char* tb2 = tids2 + (size_t)b * 2048 * 512 + (q0g + llo) * 512;
  const float* bb = bias + b * 2048;
  const float LOG2E = 1.4426950408889634f;

  unsigned short* pbuf = (unsigned short*)(smem + 32768) + w * 640;  // [16 q][40]
  float* obuf = (float*)smem;                                         // merge: 4 slots x 64 x 16
  float* mlbuf = (float*)(smem + 16384);                              // merge: 4 slots x 16 x 2

  const int slr = lane >> 3;
  const int slc = 8 * ((lane & 7) ^ slr);
  auto stage = [&](int buf, int ktg) {
    unsigned short* Kb = (unsigned short*)(smem + buf * 16384) + w * 512;
    unsigned short* Vb = (unsigned short*)(smem + buf * 16384 + 8192) + w * 512;
    gload16(khb + (size_t)(ktg + w * 8 + slr) * 64 + slc, Kb);
    gload16(vtb + (size_t)(w * 8 + slr) * 2048 + ktg + slc, Vb);
  };

  bf16x8 qf[3][2];
#pragma unroll
  for (int t = 0; t < 3; t++)
#pragma unroll
    for (int kk = 0; kk < 2; kk++)
      qf[t][kk] = ld8(qt + ((size_t)(bh * 3 + t) * 2048 + q0g + llo) * 64 + kk * 32 + lhi * 8);

  f32x4 oacc[4];  // O^T: col=q(llo), rows 16*nfd + 4*lhi + r
#pragma unroll
  for (int i = 0; i < 4; i++) oacc[i] = (f32x4){0.f, 0.f, 0.f, 0.f};
  float mrow = -1e30f, lrow = 0.f;  // mrow group-uniform; lrow per-lane PARTIAL

  stage(0, 0);
  __syncthreads();

  for (int kt = 0; kt < 2048; kt += 64) {
    const int cur = (kt >> 6) & 1;
    if (kt + 64 < 2048) stage(cur ^ 1, kt + 64);
    const char* Kb = smem + cur * 16384;
    const char* Vb = smem + cur * 16384 + 8192;
    const int kcol = kt + s * 32;           // this wave's 32-col half (global k)
    const int koff = kcol >> 2;

    const unsigned int tc0 = tb2[koff + lhi];
    const unsigned int tc1 = tb2[koff + 4 + lhi];

    bf16x8 kf[2][2];
#pragma unroll
    for (int nf = 0; nf < 2; nf++)
#pragma unroll
      for (int kk = 0; kk < 2; kk++)
        kf[nf][kk] = lds_swz(Kb, s * 32 + 16 * nf + llo, kk * 64 + lhi * 16);

    // S^T[k][q] — MFMA cluster under raised priority (T5)
    f32x4 logit[2];
    __builtin_amdgcn_s_setprio(1);
#pragma unroll
    for (int t = 0; t < 3; t++) {
      f32x4 s0 = (f32x4){0.f, 0.f, 0.f, 0.f}, s1 = (f32x4){0.f, 0.f, 0.f, 0.f};
      s0 = __builtin_amdgcn_mfma_f32_16x16x32_bf16(kf[0][0], qf[t][0], s0, 0, 0, 0);
      s0 = __builtin_amdgcn_mfma_f32_16x16x32_bf16(kf[0][1], qf[t][1], s0, 0, 0, 0);
      s1 = __builtin_amdgcn_mfma_f32_16x16x32_bf16(kf[1][0], qf[t][0], s1, 0, 0, 0);
      s1 = __builtin_amdgcn_mfma_f32_16x16x32_bf16(kf[1][1], qf[t][1], s1, 0, 0, 0);
      if (t == 0) { logit[0] = s0; logit[1] = s1; }
      else {
#pragma unroll
        for (int r = 0; r < 4; r++) {
          logit[0][r] = (((tc0 >> (2 * r)) & 3) == (unsigned)t) ? s0[r] : logit[0][r];
          logit[1][r] = (((tc1 >> (2 * r)) & 3) == (unsigned)t) ? s1[r] : logit[1][r];
        }
      }
    }
    __builtin_amdgcn_s_setprio(0);
    const f32x4 b0 = *reinterpret_cast<const f32x4*>(bb + kcol + 4 * lhi);
    const f32x4 b1 = *reinterpret_cast<const f32x4*>(bb + kcol + 16 + 4 * lhi);
#pragma unroll
    for (int r = 0; r < 4; r++) { logit[0][r] += b0[r]; logit[1][r] += b1[r]; }

    // defer-max (T13): rescale only when tile-max exceeds mrow+8
    float pmax = fmaxf(fmaxf(fmaxf(logit[0][0], logit[0][1]), fmaxf(logit[0][2], logit[0][3])),
                       fmaxf(fmaxf(logit[1][0], logit[1][1]), fmaxf(logit[1][2], logit[1][3])));
    if (__any(pmax > mrow + 8.f)) {
      float gmax = fmaxf(pmax, __shfl_xor(pmax, 16));
      gmax = fmaxf(gmax, __shfl_xor(gmax, 32));
      const float mn = fmaxf(mrow, gmax);
      const float fr = exp2f((mrow - mn) * LOG2E);
      mrow = mn;
      lrow *= fr;
#pragma unroll
      for (int nfd = 0; nfd < 4; nfd++)
#pragma unroll
        for (int r = 0; r < 4; r++) oacc[nfd][r] *= fr;
    }
    const float mnl = mrow * LOG2E;
    float rs = 0.f;
#pragma unroll
    for (int nf = 0; nf < 2; nf++)
#pragma unroll
      for (int r = 0; r < 4; r++) {
        const float p = exp2f(logit[nf][r] * LOG2E - mnl);
        logit[nf][r] = p;
        rs += p;
      }
    lrow += rs;  // per-lane partial; reduced after loop

    // P^T -> pbuf[q][k] (per-wave buffer, no barrier)
#pragma unroll
    for (int nf = 0; nf < 2; nf++) {
      unsigned int* pw = reinterpret_cast<unsigned int*>(pbuf + llo * 40 + 16 * nf + 4 * lhi);
      pw[0] = pk2(logit[nf][0], logit[nf][1]);
      pw[1] = pk2(logit[nf][2], logit[nf][3]);
    }
    const bf16x8 pa = *reinterpret_cast<const bf16x8*>(pbuf + llo * 40 + lhi * 8);
    __builtin_amdgcn_s_setprio(1);
#pragma unroll
    for (int nfd = 0; nfd < 4; nfd++) {
      const bf16x8 vf = lds_swz(Vb, 16 * nfd + llo, s * 64 + lhi * 16);
      oacc[nfd] = __builtin_amdgcn_mfma_f32_16x16x32_bf16(vf, pa, oacc[nfd], 0, 0, 0);
    }
    __builtin_amdgcn_s_setprio(0);
    __syncthreads();  // all waves done with cur; next-tile stage loads drained
  }
  // finalize lrow across the 4-lane q-group
  lrow += __shfl_xor(lrow, 16);
  lrow += __shfl_xor(lrow, 32);

  // ---- merge the 2 k-phases per q-subtile via LDS (scalar m/l) ----
  auto write_slot = [&](int slot) {
    float* o = obuf + (slot * 64 + lane) * 16;
#pragma unroll
    for (int nfd = 0; nfd < 4; nfd++)
      *reinterpret_cast<f32x4*>(o + nfd * 4) = oacc[nfd];
    if (lhi == 0) {
      mlbuf[slot * 32 + llo * 2] = mrow;
      mlbuf[slot * 32 + llo * 2 + 1] = lrow;
    }
  };
  auto merge_slot = [&](int slot) {
    const float* o = obuf + (slot * 64 + lane) * 16;
    const float mw_ = mlbuf[slot * 32 + llo * 2];
    const float lw_ = mlbuf[slot * 32 + llo * 2 + 1];
    const float M = fmaxf(mrow, mw_);
    const float fa = exp2f((mrow - M) * LOG2E);
    const float fb = exp2f((mw_ - M) * LOG2E);
    mrow = M;
    lrow = lrow * fa + lw_ * fb;
#pragma unroll
    for (int nfd = 0; nfd < 4; nfd++)
#pragma unroll
      for (int r = 0; r < 4; r++)
        oacc[nfd][r] = oacc[nfd][r] * fa + o[nfd * 4 + r] * fb;
  };
  if (s == 1) write_slot(qs);
  __syncthreads();
  if (s == 0) {
    merge_slot(qs);
    const float invl = 1.f / lrow;
    unsigned short* xo = xout + ((size_t)bh * 2048 + q0g + llo) * 64 + 4 * lhi;
#pragma unroll
    for (int nfd = 0; nfd < 4; nfd++) {
      u32x2 pk;
      pk[0] = pk2(oacc[nfd][0] * invl, oacc[nfd][1] * invl);
      pk[1] = pk2(oacc[nfd][2] * invl, oacc[nfd][3] * invl);
      *reinterpret_cast<u32x2*>(xo + 16 * nfd) = pk;
    }
  }
}

// ---------------- P5: out = x @ Wo + bo  (f32 out) ----------------
__global__ __launch_bounds__(256) void out_gemm(const unsigned short* __restrict__ xbf,
                                                const unsigned short* __restrict__ WoT,
                                                const float* __restrict__ bo,
                                                float* __restrict__ out) {
  const int m0 = blockIdx.x * 128;
  const int n0 = blockIdx.y * 64;
  const int wave = threadIdx.x >> 6, lane = threadIdx.x & 63;
  const int mw = wave >> 1, nw = wave & 1;
  const int lhi = lane >> 4, llo = lane & 15;
  f32x4 acc[4][2];
#pragma unroll
  for (int i = 0; i < 4; i++)
#pragma unroll
    for (int j = 0; j < 2; j++) acc[i][j] = (f32x4){0.f, 0.f, 0.f, 0.f};
  const int arow = m0 + mw * 64 + llo;
  const int bb = arow >> 11, l = arow & 2047;
  const int brow = n0 + nw * 32 + llo;
  for (int k0 = 0; k0 < 512; k0 += 32) {
    const int kk = k0 + lhi * 8;
    const int hk = kk >> 6, d0 = kk & 63;
    bf16x8 a[4], b[2];
#pragma unroll
    for (int mf = 0; mf < 4; mf++)
      a[mf] = ld8(xbf + ((bb * 8 + hk) * 2048 + l + 16 * mf) * 64 + d0);
#pragma unroll
    for (int nf = 0; nf < 2; nf++) b[nf] = ld8(WoT + (brow + 16 * nf) * 512 + kk);
#pragma unroll
    for (int mf = 0; mf < 4; mf++)
#pragma unroll
      for (int nf = 0; nf < 2; nf++)
        acc[mf][nf] = __builtin_amdgcn_mfma_f32_16x16x32_bf16(a[mf], b[nf], acc[mf][nf], 0, 0, 0);
  }
#pragma unroll
  for (int mf = 0; mf < 4; mf++)
#pragma unroll
    for (int nf = 0; nf < 2; nf++) {
      const int col = n0 + nw * 32 + 16 * nf + llo;
      const float bv_ = bo[col];
#pragma unroll
      for (int r = 0; r < 4; r++) {
        const int row = m0 + mw * 64 + 16 * mf + lhi * 4 + r;
        out[row * 512 + col] = acc[mf][nf][r] + bv_;
      }
    }
}

extern "C" void kernel_launch(void* const* d_in, const int* in_sizes, int n_in,
                              void* d_out, int out_size, void* d_ws, size_t ws_size,
                              hipStream_t stream) {
  const float* query = (const float*)d_in[0];
  const float* bias  = (const float*)d_in[1];
  const int*   tids  = (const int*)d_in[2];
  const float* Wq = (const float*)d_in[3];
  const float* bq = (const float*)d_in[4];
  const float* Wk = (const float*)d_in[5];
  const float* bk = (const float*)d_in[6];
  const float* Wv = (const float*)d_in[7];
  const float* bv = (const float*)d_in[8];
  const float* Wo = (const float*)d_in[9];
  const float* bo = (const float*)d_in[10];
  const float* tw = (const float*)d_in[11];
  float* out = (float*)d_out;

  char* ws = (char*)d_ws;
  size_t off = 0;
  auto take = [&](size_t bytes) { char* p = ws + off; off = (off + bytes + 255) & ~(size_t)255; return p; };
  unsigned short* q_bf   = (unsigned short*)take((size_t)4096 * 512 * 2);
  unsigned short* WT_bf  = (unsigned short*)take((size_t)3 * 512 * 512 * 2);
  unsigned short* WoT_bf = (unsigned short*)take((size_t)512 * 512 * 2);
  unsigned short* twT_bf = (unsigned short*)take((size_t)3 * 8 * 64 * 64 * 2);
  unsigned short* qh_bf  = (unsigned short*)take((size_t)2 * 8 * 2048 * 64 * 2);
  unsigned short* kh_bf  = (unsigned short*)take((size_t)2 * 8 * 2048 * 64 * 2);
  unsigned short* vhT_bf = (unsigned short*)take((size_t)2 * 8 * 64 * 2048 * 2);
  unsigned short* qt_bf  = (unsigned short*)take((size_t)2 * 8 * 3 * 2048 * 64 * 2);
  unsigned short* x_bf   = (unsigned short*)take((size_t)2 * 8 * 2048 * 64 * 2);
  unsigned char*  tids2  = (unsigned char*)take((size_t)2 * 2048 * 512);
  (void)ws_size; (void)in_sizes; (void)n_in; (void)out_size;

  prep<<<dim3(1304), dim3(256), 0, stream>>>(query, tids, Wq, Wk, Wv, Wo, tw,
                                             q_bf, WT_bf, WoT_bf, twT_bf, tids2);
  qkv_gemm<<<dim3(32, 12), dim3(256), 0, stream>>>(q_bf, WT_bf, bq, bk, bv,
                                                   qh_bf, kh_bf, vhT_bf);
  qt_gemm<<<dim3(16, 16, 3), dim3(256), 0, stream>>>(qh_bf, twT_bf, qt_bf);
  flash_attn<<<dim3(512), dim3(512), 0, stream>>>(qt_bf, kh_bf, vhT_bf, tids2, bias, x_bf);
  out_gemm<<<dim3(32, 8), dim3(256), 0, stream>>>(x_bf, WoT_bf, bo, out);
}

// Round 12
// 227.162 us; speedup vs baseline: 1.0060x; 1.0060x over previous
//
#include <hip/hip_runtime.h>
#include <hip/hip_bf16.h>

// Typed-relation MHA, MI355X.  B=2 L=2048 HID=512 NH=8 DH=64 T=3.
// Pipeline: prep -> QKV gemm (writes V^T) -> flash attn (qt fused) -> out gemm. 4 launches.
// R3/R9: tight VGPR caps -> spill (WRITE_SIZE balloons). R6: TLP not the fix.
// R10: block-shared LDS-staged K/V -> flash 167->74.6us. R11: setprio ~null (revert);
//      qkv 128x128 null; aux block constant ~150us across ALL restructures.
// R12: fuse qt_gemm into flash prologue (24 MFMA mini-GEMM per wave + LDS repack);
//      delta in total attributes qt's true cost; flash row attributes prologue cost.

typedef __attribute__((ext_vector_type(4))) float f32x4;
typedef __attribute__((ext_vector_type(8))) short bf16x8;
typedef __attribute__((ext_vector_type(4))) unsigned short u16x4;
typedef __attribute__((ext_vector_type(2))) unsigned int u32x2;

static __device__ __forceinline__ unsigned short f2bf(float x) {
  __hip_bfloat16 h = __float2bfloat16(x);
  return *reinterpret_cast<unsigned short*>(&h);
}
static __device__ __forceinline__ unsigned int pk2(float lo, float hi) {
  return (unsigned int)f2bf(lo) | ((unsigned int)f2bf(hi) << 16);
}
static __device__ __forceinline__ bf16x8 ld8(const unsigned short* p) {
  return *reinterpret_cast<const bf16x8*>(p);
}
// async global->LDS, 16B/lane; HW writes lds_base + lane*16 (base must be wave-uniform)
static __device__ __forceinline__ void gload16(const unsigned short* g, unsigned short* l) {
  __builtin_amdgcn_global_load_lds((const __attribute__((address_space(1))) void*)g,
                                   (__attribute__((address_space(3))) void*)l, 16, 0, 0);
}
// swizzled LDS tile read: tile rows are 128B; byte ^= (row&7)<<4 (G4 recipe)
static __device__ __forceinline__ bf16x8 lds_swz(const char* base, int row, int colbyte) {
  return *reinterpret_cast<const bf16x8*>(base + row * 128 + (colbyte ^ ((row & 7) << 4)));
}

// ---------------- P0: prep = W transposes + query cast + typed_ids pack ----------------
__global__ __launch_bounds__(256) void prep(
    const float* __restrict__ query, const int* __restrict__ tids,
    const float* __restrict__ Wq, const float* __restrict__ Wk,
    const float* __restrict__ Wv, const float* __restrict__ Wo,
    const float* __restrict__ tw,
    unsigned short* __restrict__ q_bf,
    unsigned short* __restrict__ WT_bf,     // [3][512 n][512 k]
    unsigned short* __restrict__ WoT_bf,    // [512 n][512 k]
    unsigned short* __restrict__ twT_bf,    // [3][8][64 e][64 d]
    unsigned char* __restrict__ tids2) {    // [B,L,L/4]
  const int bid = blockIdx.x;
  const int t = threadIdx.x;
  if (bid < 280) {
    __shared__ float tile[64][65];
    const float* src; unsigned short* dst; int lds_, ldd_;
    if (bid < 256) {
      const int m = bid >> 6, tl = bid & 63;
      const int k0 = (tl >> 3) * 64, n0 = (tl & 7) * 64;
      const float* W = (m == 0) ? Wq : (m == 1) ? Wk : (m == 2) ? Wv : Wo;
      src = W + k0 * 512 + n0;
      dst = ((m < 3) ? WT_bf + m * 512 * 512 : WoT_bf) + n0 * 512 + k0;
      lds_ = 512; ldd_ = 512;
    } else {
      const int idx = bid - 256;  // t*8+h, 0..23
      src = tw + idx * 4096; dst = twT_bf + idx * 4096;
      lds_ = 64; ldd_ = 64;
    }
#pragma unroll
    for (int p = 0; p < 4; p++) {
      const int i4 = t + p * 256;
      const int row = i4 >> 4, c4 = (i4 & 15) * 4;
      const f32x4 v = *reinterpret_cast<const f32x4*>(src + row * lds_ + c4);
#pragma unroll
      for (int j = 0; j < 4; j++) tile[row][c4 + j] = v[j];
    }
    __syncthreads();
#pragma unroll
    for (int p = 0; p < 2; p++) {
      const int i8 = t + p * 256;
      const int n = i8 >> 3, k8 = (i8 & 7) * 8;
      bf16x8 o;
#pragma unroll
      for (int j = 0; j < 8; j++) o[j] = (short)f2bf(tile[k8 + j][n]);
      *reinterpret_cast<bf16x8*>(dst + n * ldd_ + k8) = o;
    }
    return;
  }
  const int nconv = (gridDim.x - 280) * 256;
  const int tid = (bid - 280) * 256 + t;
  for (int i = tid; i < 4096 * 512 / 4; i += nconv) {
    const f32x4 v = *reinterpret_cast<const f32x4*>(query + (size_t)i * 4);
    u16x4 o;
#pragma unroll
    for (int j = 0; j < 4; j++) o[j] = f2bf(v[j]);
    *reinterpret_cast<u16x4*>(q_bf + (size_t)i * 4) = o;
  }
  for (int i = tid; i < 2 * 2048 * 512 / 4; i += nconv) {
    uchar4 o;
#pragma unroll
    for (int j = 0; j < 4; j++) {
      const int4 v = *reinterpret_cast<const int4*>(tids + (size_t)(i * 4 + j) * 4);
      ((unsigned char*)&o)[j] =
          (unsigned char)((v.x & 3) | ((v.y & 3) << 2) | ((v.z & 3) << 4) | ((v.w & 3) << 6));
    }
    *reinterpret_cast<uchar4*>(tids2 + (size_t)i * 4) = o;
  }
}

// ---------------- P1: fused QKV GEMM, 128x128 tile ----------------
__global__ __launch_bounds__(256, 4) void qkv_gemm(
    const unsigned short* __restrict__ Abf,  // query_bf [4096][512]
    const unsigned short* __restrict__ WT,   // [3][512 n][512 k]
    const float* __restrict__ bq, const float* __restrict__ bk, const float* __restrict__ bv,
    unsigned short* __restrict__ qh, unsigned short* __restrict__ kh,  // [B,H,L,DH]
    unsigned short* __restrict__ vhT) {      // [B,H,DH,L]
  const int m0 = blockIdx.x * 128;
  const int mat = blockIdx.y >> 2;
  const int ncb = (blockIdx.y & 3) * 128;    // col base within mat, 0..384
  const int wave = threadIdx.x >> 6, lane = threadIdx.x & 63;
  const int mw = wave >> 1, nw = wave & 1;
  const int lhi = lane >> 4, llo = lane & 15;
  const unsigned short* WTm = WT + mat * (512 * 512);
  f32x4 acc[4][4];
#pragma unroll
  for (int i = 0; i < 4; i++)
#pragma unroll
    for (int j = 0; j < 4; j++) acc[i][j] = (f32x4){0.f, 0.f, 0.f, 0.f};
  const int arow = m0 + mw * 64 + llo;
  const int brow = ncb + nw * 64 + llo;
  for (int k0 = 0; k0 < 512; k0 += 32) {
    const int kk = k0 + lhi * 8;
    bf16x8 a[4], b[4];
#pragma unroll
    for (int mf = 0; mf < 4; mf++) a[mf] = ld8(Abf + (arow + 16 * mf) * 512 + kk);
#pragma unroll
    for (int nf = 0; nf < 4; nf++) b[nf] = ld8(WTm + (brow + 16 * nf) * 512 + kk);
#pragma unroll
    for (int mf = 0; mf < 4; mf++)
#pragma unroll
      for (int nf = 0; nf < 4; nf++)
        acc[mf][nf] = __builtin_amdgcn_mfma_f32_16x16x32_bf16(a[mf], b[nf], acc[mf][nf], 0, 0, 0);
  }
  const int bb = m0 >> 11, lbase = (m0 & 2047) + mw * 64;
  if (mat == 2) {
    unsigned short* vt0 = vhT + (size_t)(bb * 8) * 64 * 2048;
#pragma unroll
    for (int mf = 0; mf < 4; mf++) {
#pragma unroll
      for (int nf = 0; nf < 4; nf++) {
        const int col = ncb + nw * 64 + 16 * nf + llo;  // 0..511
        const int h = col >> 6, d = col & 63;
        const float bv_ = bv[col];
        const int l0 = lbase + 16 * mf + lhi * 4;
        u32x2 pk;
        pk[0] = pk2(acc[mf][nf][0] + bv_, acc[mf][nf][1] + bv_);
        pk[1] = pk2(acc[mf][nf][2] + bv_, acc[mf][nf][3] + bv_);
        *reinterpret_cast<u32x2*>(vt0 + ((size_t)h * 64 + d) * 2048 + l0) = pk;
      }
    }
    return;
  }
  const float* bias = (mat == 0) ? bq : bk;
  unsigned short* dst = (mat == 0) ? qh : kh;
  const float scale = (mat == 0) ? 0.125f : 1.0f;
#pragma unroll
  for (int mf = 0; mf < 4; mf++) {
#pragma unroll
    for (int nf = 0; nf < 4; nf++) {
      const int col = ncb + nw * 64 + 16 * nf + llo;
      const int h = col >> 6, d = col & 63;
      const float bv_ = bias[col];
#pragma unroll
      for (int r = 0; r < 4; r++) {
        const int l = lbase + 16 * mf + lhi * 4 + r;
        const float val = (acc[mf][nf][r] + bv_) * scale;
        dst[(((size_t)(bb * 8 + h) * 2048) + l) * 64 + d] = f2bf(val);
      }
    }
  }
}

// ---------------- P4: flash attention, qt fused in prologue (R12) ----------------
// grid 512: bh = bid&15, qtile = bid>>4. Block 512 thr = 8 waves:
// qs = w>>1 (4 q-subtiles x 16 rows), s = w&1 (k-phase half of each staged tile).
// Prologue: qt fragments computed in-kernel (24 MFMA mini-GEMM + LDS repack through
// the dbuf region, which is idle pre-staging). Loop identical to R10 (no setprio).
__global__ __launch_bounds__(512, 4) void flash_attn(
    const unsigned short* __restrict__ qh,    // [B,H,L,D] (scaled by 0.125)
    const unsigned short* __restrict__ twT,   // [3][8][64 e][64 d]
    const unsigned short* __restrict__ kh,    // [B,H,L,D]
    const unsigned short* __restrict__ vhT,   // [B,H,D,L]
    const unsigned char* __restrict__ tids2,  // [B,L,L/4] 2-bit codes
    const float* __restrict__ bias,           // [B,L]
    unsigned short* __restrict__ xout) {      // [B,H,L,D]
  __shared__ char smem[43008];  // dbuf 2x16KB (K 8KB + V 8KB each) + pbuf 8x1280B
  const int bh = blockIdx.x & 15;
  const int qtile = blockIdx.x >> 4;
  const int b = bh >> 3, h = bh & 7;
  const int w = threadIdx.x >> 6;
  const int qs = w >> 1, s = w & 1;
  const int lane = threadIdx.x & 63;
  const int lhi = lane >> 4, llo = lane & 15;
  const int q0g = qtile * 64 + qs * 16;
  const unsigned short* khb = kh + (size_t)bh * 2048 * 64;
  const unsigned short* vtb = vhT + (size_t)bh * 64 * 2048;
  const unsigned char* tb2 = tids2 + (size_t)b * 2048 * 512 + (q0g + llo) * 512;
  const float* bb = bias + b * 2048;
  const float LOG2E = 1.4426950408889634f;

  unsigned short* pbuf = (unsigned short*)(smem + 32768) + w * 640;  // [16 q][40]
  float* obuf = (float*)smem;                                         // merge: 4 slots x 64 x 16
  float* mlbuf = (float*)(smem + 16384);                              // merge: 4 slots x 16 x 2

  // ---- fused qt prologue: qt[q,e] = sum_d qh[q,d] * tw[t][d,e], per-wave mini-GEMM.
  // Swapped operands (A=twT rows=e, B=qh rows=q) -> acc col = q(llo), row = e.
  // Repack to B-fragment layout via per-wave LDS buffer in the (pre-staging) dbuf area.
  bf16x8 qf[3][2];
  {
    unsigned short* qbuf = (unsigned short*)smem + w * 1280;  // [16 q][80] shorts, per-wave
    bf16x8 qhB[2];
#pragma unroll
    for (int kk = 0; kk < 2; kk++)
      qhB[kk] = ld8(qh + ((size_t)bh * 2048 + q0g + llo) * 64 + kk * 32 + lhi * 8);
#pragma unroll
    for (int t = 0; t < 3; t++) {
      const unsigned short* twb = twT + (size_t)(t * 8 + h) * 4096;
      f32x4 qacc[4];
#pragma unroll
      for (int mfe = 0; mfe < 4; mfe++) qacc[mfe] = (f32x4){0.f, 0.f, 0.f, 0.f};
#pragma unroll
      for (int mfe = 0; mfe < 4; mfe++)
#pragma unroll
        for (int kk = 0; kk < 2; kk++) {
          const bf16x8 ta = ld8(twb + (16 * mfe + llo) * 64 + kk * 32 + lhi * 8);
          qacc[mfe] = __builtin_amdgcn_mfma_f32_16x16x32_bf16(ta, qhB[kk], qacc[mfe], 0, 0, 0);
        }
#pragma unroll
      for (int mfe = 0; mfe < 4; mfe++) {
        u32x2 pk;
        pk[0] = pk2(qacc[mfe][0], qacc[mfe][1]);
        pk[1] = pk2(qacc[mfe][2], qacc[mfe][3]);
        *reinterpret_cast<u32x2*>(qbuf + llo * 80 + 16 * mfe + 4 * lhi) = pk;
      }
      // same-wave DS write->read: in-order, no barrier
#pragma unroll
      for (int kk = 0; kk < 2; kk++)
        qf[t][kk] = ld8(qbuf + llo * 80 + kk * 32 + lhi * 8);
    }
  }
  __syncthreads();  // all waves done with qbuf before staging overwrites dbuf region

  const int slr = lane >> 3;
  const int slc = 8 * ((lane & 7) ^ slr);
  auto stage = [&](int buf, int ktg) {
    unsigned short* Kb = (unsigned short*)(smem + buf * 16384) + w * 512;
    unsigned short* Vb = (unsigned short*)(smem + buf * 16384 + 8192) + w * 512;
    gload16(khb + (size_t)(ktg + w * 8 + slr) * 64 + slc, Kb);
    gload16(vtb + (size_t)(w * 8 + slr) * 2048 + ktg + slc, Vb);
  };

  f32x4 oacc[4];  // O^T: col=q(llo), rows 16*nfd + 4*lhi + r
#pragma unroll
  for (int i = 0; i < 4; i++) oacc[i] = (f32x4){0.f, 0.f, 0.f, 0.f};
  float mrow = -1e30f, lrow = 0.f;  // mrow group-uniform; lrow per-lane PARTIAL

  stage(0, 0);
  __syncthreads();

  for (int kt = 0; kt < 2048; kt += 64) {
    const int cur = (kt >> 6) & 1;
    if (kt + 64 < 2048) stage(cur ^ 1, kt + 64);
    const char* Kb = smem + cur * 16384;
    const char* Vb = smem + cur * 16384 + 8192;
    const int kcol = kt + s * 32;           // this wave's 32-col half (global k)
    const int koff = kcol >> 2;

    const unsigned int tc0 = tb2[koff + lhi];
    const unsigned int tc1 = tb2[koff + 4 + lhi];

    bf16x8 kf[2][2];
#pragma unroll
    for (int nf = 0; nf < 2; nf++)
#pragma unroll
      for (int kk = 0; kk < 2; kk++)
        kf[nf][kk] = lds_swz(Kb, s * 32 + 16 * nf + llo, kk * 64 + lhi * 16);

    // S^T[k][q]
    f32x4 logit[2];
#pragma unroll
    for (int t = 0; t < 3; t++) {
      f32x4 s0 = (f32x4){0.f, 0.f, 0.f, 0.f}, s1 = (f32x4){0.f, 0.f, 0.f, 0.f};
      s0 = __builtin_amdgcn_mfma_f32_16x16x32_bf16(kf[0][0], qf[t][0], s0, 0, 0, 0);
      s0 = __builtin_amdgcn_mfma_f32_16x16x32_bf16(kf[0][1], qf[t][1], s0, 0, 0, 0);
      s1 = __builtin_amdgcn_mfma_f32_16x16x32_bf16(kf[1][0], qf[t][0], s1, 0, 0, 0);
      s1 = __builtin_amdgcn_mfma_f32_16x16x32_bf16(kf[1][1], qf[t][1], s1, 0, 0, 0);
      if (t == 0) { logit[0] = s0; logit[1] = s1; }
      else {
#pragma unroll
        for (int r = 0; r < 4; r++) {
          logit[0][r] = (((tc0 >> (2 * r)) & 3) == (unsigned)t) ? s0[r] : logit[0][r];
          logit[1][r] = (((tc1 >> (2 * r)) & 3) == (unsigned)t) ? s1[r] : logit[1][r];
        }
      }
    }
    const f32x4 b0 = *reinterpret_cast<const f32x4*>(bb + kcol + 4 * lhi);
    const f32x4 b1 = *reinterpret_cast<const f32x4*>(bb + kcol + 16 + 4 * lhi);
#pragma unroll
    for (int r = 0; r < 4; r++) { logit[0][r] += b0[r]; logit[1][r] += b1[r]; }

    // defer-max (T13): rescale only when tile-max exceeds mrow+8
    float pmax = fmaxf(fmaxf(fmaxf(logit[0][0], logit[0][1]), fmaxf(logit[0][2], logit[0][3])),
                       fmaxf(fmaxf(logit[1][0], logit[1][1]), fmaxf(logit[1][2], logit[1][3])));
    if (__any(pmax > mrow + 8.f)) {
      float gmax = fmaxf(pmax, __shfl_xor(pmax, 16));
      gmax = fmaxf(gmax, __shfl_xor(gmax, 32));
      const float mn = fmaxf(mrow, gmax);
      const float fr = exp2f((mrow - mn) * LOG2E);
      mrow = mn;
      lrow *= fr;
#pragma unroll
      for (int nfd = 0; nfd < 4; nfd++)
#pragma unroll
        for (int r = 0; r < 4; r++) oacc[nfd][r] *= fr;
    }
    const float mnl = mrow * LOG2E;
    float rs = 0.f;
#pragma unroll
    for (int nf = 0; nf < 2; nf++)
#pragma unroll
      for (int r = 0; r < 4; r++) {
        const float p = exp2f(logit[nf][r] * LOG2E - mnl);
        logit[nf][r] = p;
        rs += p;
      }
    lrow += rs;  // per-lane partial; reduced after loop

    // P^T -> pbuf[q][k] (per-wave buffer, no barrier)
#pragma unroll
    for (int nf = 0; nf < 2; nf++) {
      unsigned int* pw = reinterpret_cast<unsigned int*>(pbuf + llo * 40 + 16 * nf + 4 * lhi);
      pw[0] = pk2(logit[nf][0], logit[nf][1]);
      pw[1] = pk2(logit[nf][2], logit[nf][3]);
    }
    const bf16x8 pa = *reinterpret_cast<const bf16x8*>(pbuf + llo * 40 + lhi * 8);
#pragma unroll
    for (int nfd = 0; nfd < 4; nfd++) {
      const bf16x8 vf = lds_swz(Vb, 16 * nfd + llo, s * 64 + lhi * 16);
      oacc[nfd] = __builtin_amdgcn_mfma_f32_16x16x32_bf16(vf, pa, oacc[nfd], 0, 0, 0);
    }
    __syncthreads();  // all waves done with cur; next-tile stage loads drained
  }
  // finalize lrow across the 4-lane q-group
  lrow += __shfl_xor(lrow, 16);
  lrow += __shfl_xor(lrow, 32);

  // ---- merge the 2 k-phases per q-subtile via LDS (scalar m/l) ----
  auto write_slot = [&](int slot) {
    float* o = obuf + (slot * 64 + lane) * 16;
#pragma unroll
    for (int nfd = 0; nfd < 4; nfd++)
      *reinterpret_cast<f32x4*>(o + nfd * 4) = oacc[nfd];
    if (lhi == 0) {
      mlbuf[slot * 32 + llo * 2] = mrow;
      mlbuf[slot * 32 + llo * 2 + 1] = lrow;
    }
  };
  auto merge_slot = [&](int slot) {
    const float* o = obuf + (slot * 64 + lane) * 16;
    const float mw_ = mlbuf[slot * 32 + llo * 2];
    const float lw_ = mlbuf[slot * 32 + llo * 2 + 1];
    const float M = fmaxf(mrow, mw_);
    const float fa = exp2f((mrow - M) * LOG2E);
    const float fb = exp2f((mw_ - M) * LOG2E);
    mrow = M;
    lrow = lrow * fa + lw_ * fb;
#pragma unroll
    for (int nfd = 0; nfd < 4; nfd++)
#pragma unroll
      for (int r = 0; r < 4; r++)
        oacc[nfd][r] = oacc[nfd][r] * fa + o[nfd * 4 + r] * fb;
  };
  if (s == 1) write_slot(qs);
  __syncthreads();
  if (s == 0) {
    merge_slot(qs);
    const float invl = 1.f / lrow;
    unsigned short* xo = xout + ((size_t)bh * 2048 + q0g + llo) * 64 + 4 * lhi;
#pragma unroll
    for (int nfd = 0; nfd < 4; nfd++) {
      u32x2 pk;
      pk[0] = pk2(oacc[nfd][0] * invl, oacc[nfd][1] * invl);
      pk[1] = pk2(oacc[nfd][2] * invl, oacc[nfd][3] * invl);
      *reinterpret_cast<u32x2*>(xo + 16 * nfd) = pk;
    }
  }
}

// ---------------- P5: out = x @ Wo + bo  (f32 out) ----------------
__global__ __launch_bounds__(256) void out_gemm(const unsigned short* __restrict__ xbf,
                                                const unsigned short* __restrict__ WoT,
                                                const float* __restrict__ bo,
                                                float* __restrict__ out) {
  const int m0 = blockIdx.x * 128;
  const int n0 = blockIdx.y * 64;
  const int wave = threadIdx.x >> 6, lane = threadIdx.x & 63;
  const int mw = wave >> 1, nw = wave & 1;
  const int lhi = lane >> 4, llo = lane & 15;
  f32x4 acc[4][2];
#pragma unroll
  for (int i = 0; i < 4; i++)
#pragma unroll
    for (int j = 0; j < 2; j++) acc[i][j] = (f32x4){0.f, 0.f, 0.f, 0.f};
  const int arow = m0 + mw * 64 + llo;
  const int bb = arow >> 11, l = arow & 2047;
  const int brow = n0 + nw * 32 + llo;
  for (int k0 = 0; k0 < 512; k0 += 32) {
    const int kk = k0 + lhi * 8;
    const int hk = kk >> 6, d0 = kk & 63;
    bf16x8 a[4], b[2];
#pragma unroll
    for (int mf = 0; mf < 4; mf++)
      a[mf] = ld8(xbf + ((bb * 8 + hk) * 2048 + l + 16 * mf) * 64 + d0);
#pragma unroll
    for (int nf = 0; nf < 2; nf++) b[nf] = ld8(WoT + (brow + 16 * nf) * 512 + kk);
#pragma unroll
    for (int mf = 0; mf < 4; mf++)
#pragma unroll
      for (int nf = 0; nf < 2; nf++)
        acc[mf][nf] = __builtin_amdgcn_mfma_f32_16x16x32_bf16(a[mf], b[nf], acc[mf][nf], 0, 0, 0);
  }
#pragma unroll
  for (int mf = 0; mf < 4; mf++)
#pragma unroll
    for (int nf = 0; nf < 2; nf++) {
      const int col = n0 + nw * 32 + 16 * nf + llo;
      const float bv_ = bo[col];
#pragma unroll
      for (int r = 0; r < 4; r++) {
        const int row = m0 + mw * 64 + 16 * mf + lhi * 4 + r;
        out[row * 512 + col] = acc[mf][nf][r] + bv_;
      }
    }
}

extern "C" void kernel_launch(void* const* d_in, const int* in_sizes, int n_in,
                              void* d_out, int out_size, void* d_ws, size_t ws_size,
                              hipStream_t stream) {
  const float* query = (const float*)d_in[0];
  const float* bias  = (const float*)d_in[1];
  const int*   tids  = (const int*)d_in[2];
  const float* Wq = (const float*)d_in[3];
  const float* bq = (const float*)d_in[4];
  const float* Wk = (const float*)d_in[5];
  const float* bk = (const float*)d_in[6];
  const float* Wv = (const float*)d_in[7];
  const float* bv = (const float*)d_in[8];
  const float* Wo = (const float*)d_in[9];
  const float* bo = (const float*)d_in[10];
  const float* tw = (const float*)d_in[11];
  float* out = (float*)d_out;

  char* ws = (char*)d_ws;
  size_t off = 0;
  auto take = [&](size_t bytes) { char* p = ws + off; off = (off + bytes + 255) & ~(size_t)255; return p; };
  unsigned short* q_bf   = (unsigned short*)take((size_t)4096 * 512 * 2);
  unsigned short* WT_bf  = (unsigned short*)take((size_t)3 * 512 * 512 * 2);
  unsigned short* WoT_bf = (unsigned short*)take((size_t)512 * 512 * 2);
  unsigned short* twT_bf = (unsigned short*)take((size_t)3 * 8 * 64 * 64 * 2);
  unsigned short* qh_bf  = (unsigned short*)take((size_t)2 * 8 * 2048 * 64 * 2);
  unsigned short* kh_bf  = (unsigned short*)take((size_t)2 * 8 * 2048 * 64 * 2);
  unsigned short* vhT_bf = (unsigned short*)take((size_t)2 * 8 * 64 * 2048 * 2);
  unsigned short* x_bf   = (unsigned short*)take((size_t)2 * 8 * 2048 * 64 * 2);
  unsigned char*  tids2  = (unsigned char*)take((size_t)2 * 2048 * 512);
  (void)ws_size; (void)in_sizes; (void)n_in; (void)out_size;

  prep<<<dim3(1304), dim3(256), 0, stream>>>(query, tids, Wq, Wk, Wv, Wo, tw,
                                             q_bf, WT_bf, WoT_bf, twT_bf, tids2);
  qkv_gemm<<<dim3(32, 12), dim3(256), 0, stream>>>(q_bf, WT_bf, bq, bk, bv,
                                                   qh_bf, kh_bf, vhT_bf);
  flash_attn<<<dim3(512), dim3(512), 0, stream>>>(qh_bf, twT_bf, kh_bf, vhT_bf,
                                                  tids2, bias, x_bf);
  out_gemm<<<dim3(32, 8), dim3(256), 0, stream>>>(x_bf, WoT_bf, bo, out);
}